// Round 1
// baseline (541.764 us; speedup 1.0000x reference)
//
#include <hip/hip_runtime.h>

typedef unsigned short ushort_t;
typedef unsigned char u8;
typedef short bf16x8 __attribute__((ext_vector_type(8)));
typedef float f32x4 __attribute__((ext_vector_type(4)));

#define T_DIM 4
#define B_DIM 32
#define C_DIM 512
#define N_DIM 256

__device__ __forceinline__ float bf2f(ushort_t u) {
  union { unsigned int i; float f; } x;
  x.i = ((unsigned int)u) << 16;
  return x.f;
}
__device__ __forceinline__ ushort_t f2bf(float f) {
  unsigned int u = __float_as_uint(f);
  u = (u + 0x7FFFu + ((u >> 16) & 1u)) >> 16;
  return (ushort_t)u;
}

// async global->LDS DMA, 16B per lane, lane i lands at ldsbase + i*16
__device__ __forceinline__ void gload16(const void* g, void* l) {
  __builtin_amdgcn_global_load_lds(
      (const __attribute__((address_space(1))) unsigned int*)g,
      (__attribute__((address_space(3))) unsigned int*)l, 16, 0, 0);
}

// ---------------------------------------------------------------------------
// K0: split fp32 weights into 3 bf16 planes (hi, mid, lo). W ~= hi+mid+lo.
// ---------------------------------------------------------------------------
__global__ __launch_bounds__(256) void k0_split(
    const float* __restrict__ Wq, const float* __restrict__ Wk,
    const float* __restrict__ Wv, const float* __restrict__ Wp,
    ushort_t* __restrict__ Sqkv, ushort_t* __restrict__ Sp)
{
  int gid = blockIdx.x * 256 + threadIdx.x;   // [0, 131072)
  int w = gid >> 15;
  int off = (gid & 32767) * 8;
  const float* src = (w == 0) ? Wq : ((w == 1) ? Wk : ((w == 2) ? Wv : Wp));
  ushort_t* dst = (w < 3) ? (Sqkv + (size_t)w * 3 * 262144) : Sp;
  float wv[8];
  *(float4*)&wv[0] = *(const float4*)(src + off);
  *(float4*)&wv[4] = *(const float4*)(src + off + 4);
  ushort_t hi[8], mi[8], lo[8];
#pragma unroll
  for (int i = 0; i < 8; i++) {
    float f = wv[i];
    ushort_t h = f2bf(f);  float r  = f - bf2f(h);
    ushort_t m = f2bf(r);  float r2 = r - bf2f(m);
    ushort_t l = f2bf(r2);
    hi[i] = h; mi[i] = m; lo[i] = l;
  }
  *(uint4*)(dst + off)              = *(uint4*)&hi[0];
  *(uint4*)(dst + 262144 + off)     = *(uint4*)&mi[0];
  *(uint4*)(dst + 2 * 262144 + off) = *(uint4*)&lo[0];
}

// ---------------------------------------------------------------------------
// K1: shortcut LIF on x [T,B,C,N] (fp32) -> spikes transposed xsT8 [T,B,N,C] u8
// ---------------------------------------------------------------------------
__global__ __launch_bounds__(256) void k1_shortcut_lif(
    const float* __restrict__ x, u8* __restrict__ xsT8)
{
  const int n0 = blockIdx.x * 64;
  const int c0 = blockIdx.y * 64;
  const int b  = blockIdx.z;
  __shared__ u8 sm[64][80];
  const int tid = threadIdx.x;
  const int r  = tid >> 2;
  const int j0 = (tid & 3) * 16;
  float v[16];
#pragma unroll
  for (int i = 0; i < 16; i++) v[i] = 0.f;
  for (int t = 0; t < T_DIM; t++) {
    const float* xp = x + ((((size_t)t * B_DIM + b) * C_DIM) + c0 + r) * N_DIM + n0 + j0;
    float xv[16];
    *(float4*)&xv[0]  = *(const float4*)xp;
    *(float4*)&xv[4]  = *(const float4*)(xp + 4);
    *(float4*)&xv[8]  = *(const float4*)(xp + 8);
    *(float4*)&xv[12] = *(const float4*)(xp + 12);
    __syncthreads();
#pragma unroll
    for (int i = 0; i < 16; i++) {
      float nv = v[i] + (xv[i] - v[i]) * 0.5f;
      bool s = (nv >= 1.0f);
      v[i] = s ? 0.f : nv;
      sm[j0 + i][r] = s ? (u8)1 : (u8)0;
    }
    __syncthreads();
    union { uint4 u; u8 b[16]; } ov;
#pragma unroll
    for (int i = 0; i < 16; i++) ov.b[i] = sm[r][j0 + i];
    u8* op = xsT8 + ((((size_t)t * B_DIM + b) * N_DIM) + n0 + r) * C_DIM + c0 + j0;
    *(uint4*)op = ov.u;
  }
}

// ---------------------------------------------------------------------------
// K2: QKV conv1x1 + BN + LIF. 512 threads (8 waves), 64m x 256n block tile,
// wave tile 16m x 128n (acc[8]). A (3 bf16 planes) and B (spike u8) staged
// via async global_load_lds (linear LDS, bank-uniform reads, no swizzle).
// B kept as u8 in LDS; expanded to bf16 at frag-read via v_perm_b32 + mul,
// amortized over the 3 A-planes. One barrier per k-step, double-buffered.
// t-loop fused (LIF v-state in regs); epilogue every 16 k-steps.
//    q -> qs8[t,b,c,n] u8 ; k -> ks8[t,b,c,n] u8
//    v -> vout[t,b,h,n,d] fp32 0/1 via full-line float4 stores.
// ---------------------------------------------------------------------------
__global__ __launch_bounds__(512, 4) void k2_qkv(
    const u8* __restrict__ xsT8, const ushort_t* __restrict__ Sqkv,
    const float* __restrict__ qsc, const float* __restrict__ qbi,
    const float* __restrict__ ksc, const float* __restrict__ kbi,
    const float* __restrict__ vsc, const float* __restrict__ vbi,
    u8* __restrict__ qs8, u8* __restrict__ ks8, float* __restrict__ vout)
{
  const int mt = blockIdx.x;          // 0..23
  const int b  = blockIdx.y;          // 0..31
  const int branch = mt >> 3;         // 0=q 1=k 2=v
  const int mloc = (mt & 7) * 64;     // within branch's 512
  const ushort_t* Ws = Sqkv + (size_t)branch * 3 * 262144;
  const float* scp = (branch == 0) ? qsc : ((branch == 1) ? ksc : vsc);
  const float* bip = (branch == 0) ? qbi : ((branch == 1) ? kbi : vbi);

  __shared__ alignas(16) ushort_t As[2][3][64][32];   // 24 KB, linear
  __shared__ alignas(16) u8 Bs8[2][256][32];          // 16 KB, linear

  const int tid  = threadIdx.x;
  const int lane = tid & 63;
  const int wave = tid >> 6;
  const int wrow = (wave >> 1) * 16;   // m strip (16 rows)
  const int wcol = (wave & 1) * 128;   // n half (128 cols)
  const int frow = lane & 15;
  const int fsl  = lane >> 4;          // 8-elem slot 0..3

  const u8* Bb0 = xsT8 + (size_t)b * N_DIM * C_DIM;

  // staging chunks: 12 A-chunks (1KB = plane p, 16-row group q) over 8 waves,
  // 8 B-chunks (1KB = 32 n-rows). waves 0-3: A{wave}, A{8+wave}, B{4+wave};
  // waves 4-7: A{wave}, B{wave-4}.
  const int a0p = wave >> 2, a0q = wave & 3;
  const int arl = lane >> 2;                 // row within 16
  const int acl = (lane & 3) * 8;            // halfword col within 32
  const int brl = lane >> 1;                 // row within 32
  const int bcl = (lane & 1) * 16;           // byte col within 32
  const int cbx = (wave < 4) ? (4 + wave) : (wave - 4);

#define K2_STAGE(s_) {                                                                     \
    const int t_ = (s_) >> 4; const int kb_ = ((s_) & 15) * 32; const int bf_ = (s_) & 1;  \
    gload16(Ws + (size_t)a0p * 262144 + (size_t)(mloc + a0q * 16 + arl) * 512 + kb_ + acl, \
            &As[bf_][a0p][a0q * 16][0]);                                                   \
    if (wave < 4)                                                                          \
      gload16(Ws + 2 * 262144 + (size_t)(mloc + wave * 16 + arl) * 512 + kb_ + acl,        \
              &As[bf_][2][wave * 16][0]);                                                  \
    gload16(Bb0 + (size_t)t_ * (B_DIM * N_DIM * C_DIM) + (size_t)(cbx * 32 + brl) * 512 + kb_ + bcl, \
            &Bs8[bf_][cbx * 32][0]);                                                       \
  }

  f32x4 acc[8];
  float vst[32];
#pragma unroll
  for (int i = 0; i < 32; i++) vst[i] = 0.f;
#pragma unroll
  for (int j = 0; j < 8; j++) acc[j] = (f32x4){0.f, 0.f, 0.f, 0.f};

  // preload BN scale/bias for this thread's 4 c-rows (constant across t)
  const int crow0 = (lane >> 4) * 4;
  const int cn    = lane & 15;
  float sc4[4], bi4[4];
#pragma unroll
  for (int r = 0; r < 4; r++) {
    int c = mloc + wrow + crow0 + r;
    sc4[r] = scp[c]; bi4[r] = bip[c];
  }

  K2_STAGE(0);
  __syncthreads();

  for (int s = 0; s < 64; s++) {
    const int cur = s & 1;
    if (s < 63) K2_STAGE(s + 1);   // async into buf^1, lands during compute

    bf16x8 af[3];
    const int ar = wrow + frow;
#pragma unroll
    for (int p = 0; p < 3; p++) af[p] = *(const bf16x8*)&As[cur][p][ar][fsl * 8];

#pragma unroll
    for (int j = 0; j < 8; j++) {
      const int row = wcol + j * 16 + frow;
      uint2 raw = *(const uint2*)&Bs8[cur][row][fsl * 8];
      union { bf16x8 v; unsigned int u[4]; } bu;
      bu.u[0] = __builtin_amdgcn_perm(0u, raw.x, 0x05010400u) * 0x3F80u;
      bu.u[1] = __builtin_amdgcn_perm(0u, raw.x, 0x07030602u) * 0x3F80u;
      bu.u[2] = __builtin_amdgcn_perm(0u, raw.y, 0x05010400u) * 0x3F80u;
      bu.u[3] = __builtin_amdgcn_perm(0u, raw.y, 0x07030602u) * 0x3F80u;
#pragma unroll
      for (int p = 0; p < 3; p++)
        acc[j] = __builtin_amdgcn_mfma_f32_16x16x32_bf16(af[p], bu.v, acc[j], 0, 0, 0);
    }

    if ((s & 15) == 15) {
      // epilogue for t = s>>4
      const int t = s >> 4;
      const size_t tb = (size_t)t * B_DIM + b;
      if (branch < 2) {
        u8* dst = (branch == 0) ? qs8 : ks8;
#pragma unroll
        for (int r = 0; r < 4; r++) {
          const int c = mloc + wrow + crow0 + r;
#pragma unroll
          for (int j = 0; j < 8; j++) {
            const int n = wcol + j * 16 + cn;
            float y = acc[j][r] * sc4[r] + bi4[r];
            const int vi = j * 4 + r;
            float v = vst[vi];
            v = v + (y - v) * 0.5f;
            bool sp = (v >= 1.0f);
            vst[vi] = sp ? 0.f : v;
            dst[(tb * C_DIM + c) * N_DIM + n] = sp ? (u8)1 : (u8)0;
          }
        }
      } else {
        const int hv = mloc >> 6;
        const int d0 = wrow + crow0;
#pragma unroll
        for (int j = 0; j < 8; j++) {
          const int n = wcol + j * 16 + cn;
          float ov[4];
#pragma unroll
          for (int r = 0; r < 4; r++) {
            float y = acc[j][r] * sc4[r] + bi4[r];
            const int vi = j * 4 + r;
            float v = vst[vi];
            v = v + (y - v) * 0.5f;
            bool sp = (v >= 1.0f);
            vst[vi] = sp ? 0.f : v;
            ov[r] = sp ? 1.0f : 0.0f;
          }
          *(float4*)(vout + ((tb * 8 + hv) * N_DIM + n) * 64 + d0) =
              make_float4(ov[0], ov[1], ov[2], ov[3]);
        }
      }
#pragma unroll
      for (int j = 0; j < 8; j++) acc[j] = (f32x4){0.f, 0.f, 0.f, 0.f};
    }
    __syncthreads();
  }
#undef K2_STAGE
}

// ---------------------------------------------------------------------------
// K3: attn[ch,b,h,d,e] = (1/16) * sum_{t,n} k[d,(t,n)] * v[(t,n),e]
// ---------------------------------------------------------------------------
__global__ __launch_bounds__(256) void k3_attn(
    const u8* __restrict__ ks8, const float* __restrict__ vsp,
    float* __restrict__ attn)
{
  const int h  = blockIdx.x;
  const int b  = blockIdx.y;
  const int ch = blockIdx.z;
  __shared__ u8 KtT[64][80];
  __shared__ u8 Vt[64][80];
  const int tid = threadIdx.x;
  const int d0 = (tid >> 4) * 4;
  const int e0 = (tid & 15) * 4;
  float a[16];
#pragma unroll
  for (int i = 0; i < 16; i++) a[i] = 0.f;

  for (int tt = 0; tt < 2; tt++) {
    int t = ch * 2 + tt;
    for (int n0 = 0; n0 < 256; n0 += 64) {
      __syncthreads();
      {
        int d  = tid >> 2;
        int s0 = (tid & 3) * 16;
        union { uint4 u; u8 bvec[16]; } kb;
        kb.u = *(const uint4*)(ks8 + ((((size_t)t * B_DIM + b) * C_DIM) + h * 64 + d) * N_DIM + n0 + s0);
#pragma unroll
        for (int i = 0; i < 16; i++) KtT[s0 + i][d] = kb.bvec[i];
      }
      {
        const float* vb = vsp + ((((size_t)t * B_DIM + b) * 8 + h) * N_DIM + n0) * 64;
#pragma unroll
        for (int u = 0; u < 4; u++) {
          int chunk = tid + u * 256;
          int row = chunk >> 4;
          int eo  = (chunk & 15) * 4;
          float4 v4 = *(const float4*)(vb + (size_t)row * 64 + eo);
          Vt[row][eo + 0] = (u8)(v4.x != 0.f);
          Vt[row][eo + 1] = (u8)(v4.y != 0.f);
          Vt[row][eo + 2] = (u8)(v4.z != 0.f);
          Vt[row][eo + 3] = (u8)(v4.w != 0.f);
        }
      }
      __syncthreads();
      for (int s = 0; s < 64; s++) {
        uchar4 kb = *(const uchar4*)&KtT[s][d0];
        float kv[4] = { (float)kb.x, (float)kb.y, (float)kb.z, (float)kb.w };
        uchar4 vr = *(const uchar4*)&Vt[s][e0];
        float vv[4] = { (float)vr.x, (float)vr.y, (float)vr.z, (float)vr.w };
#pragma unroll
        for (int i = 0; i < 4; i++)
#pragma unroll
          for (int j = 0; j < 4; j++) a[i * 4 + j] += kv[i] * vv[j];
      }
    }
  }
  float* ap = attn + ((((size_t)ch * B_DIM + b) * 8 + h) * 64 + d0) * 64 + e0;
#pragma unroll
  for (int i = 0; i < 4; i++)
#pragma unroll
    for (int j = 0; j < 4; j++)
      ap[i * 64 + j] = a[i * 4 + j] * 0.0625f;
}

// ---------------------------------------------------------------------------
// K4: out[e,n] = sum_d attn[d,e]*q[d,n], attn-LIF(0.5) -> x2sT8[t,b,n,c] u8.
// n-chunk split across grid.z for 4x parallelism; vst[16] per thread.
// ---------------------------------------------------------------------------
__global__ __launch_bounds__(256) void k4_out_lif(
    const u8* __restrict__ qs8, const float* __restrict__ attn,
    u8* __restrict__ x2sT8)
{
  const int h  = blockIdx.x;
  const int b  = blockIdx.y;
  const int nc = blockIdx.z;   // 0..3
  __shared__ float At[64][68];
  __shared__ u8 Qt[64][80];
  const int tid = threadIdx.x;
  const int e0 = (tid >> 4) * 4;
  const int n0 = (tid & 15) * 4;
  float vst[16];
#pragma unroll
  for (int i = 0; i < 16; i++) vst[i] = 0.f;

  for (int t = 0; t < T_DIM; t++) {
    if ((t & 1) == 0) {
      __syncthreads();
      const float* ap = attn + ((((size_t)(t >> 1) * B_DIM + b) * 8) + h) * 4096;
      int dr = tid >> 2;
      int co = (tid & 3) * 16;
#pragma unroll
      for (int u = 0; u < 4; u++)
        *(float4*)&At[dr][co + u * 4] = *(const float4*)(ap + dr * 64 + co + u * 4);
    }
    __syncthreads();
    {
      int d  = tid >> 2;
      int so = (tid & 3) * 16;
      *(uint4*)&Qt[d][so] =
        *(const uint4*)(qs8 + ((((size_t)t * B_DIM + b) * C_DIM) + h * 64 + d) * N_DIM + nc * 64 + so);
    }
    __syncthreads();
    float acc[16];
#pragma unroll
    for (int i = 0; i < 16; i++) acc[i] = 0.f;
    for (int d = 0; d < 64; d++) {
      float4 av = *(const float4*)&At[d][e0];
      float avv[4] = { av.x, av.y, av.z, av.w };
      uchar4 qr = *(const uchar4*)&Qt[d][n0];
      float qv[4] = { (float)qr.x, (float)qr.y, (float)qr.z, (float)qr.w };
#pragma unroll
      for (int i = 0; i < 4; i++)
#pragma unroll
        for (int j = 0; j < 4; j++) acc[i * 4 + j] += avv[i] * qv[j];
    }
#pragma unroll
    for (int j = 0; j < 4; j++) {
      u8 sv[4];
#pragma unroll
      for (int i = 0; i < 4; i++) {
        int vi = i * 4 + j;
        float y = acc[i * 4 + j];
        float nv = vst[vi] + (y - vst[vi]) * 0.5f;
        bool s = (nv >= 0.5f);
        vst[vi] = s ? 0.f : nv;
        sv[i] = s ? (u8)1 : (u8)0;
      }
      int n = nc * 64 + n0 + j;
      u8* op = x2sT8 + ((((size_t)t * B_DIM + b) * N_DIM) + n) * C_DIM + h * 64 + e0;
      *(uchar4*)op = make_uchar4(sv[0], sv[1], sv[2], sv[3]);
    }
  }
}

// ---------------------------------------------------------------------------
// K5: proj conv1x1 (+bp)*scale+bias + residual -> out0 fp32. Same engine as
// new K2: 64m x 256n block, wave 16x128, async global_load_lds staging,
// u8 B in LDS with read-time bf16 expansion.
// ---------------------------------------------------------------------------
__global__ __launch_bounds__(512, 4) void k5_proj(
    const u8* __restrict__ x2sT8, const ushort_t* __restrict__ Sp,
    const float* __restrict__ bp, const float* __restrict__ psc,
    const float* __restrict__ pbi,
    const float* __restrict__ x, float* __restrict__ out0)
{
  const int mt = blockIdx.x;   // 0..7
  const int tb = blockIdx.y;   // 0..127
  const int mloc = mt * 64;

  __shared__ alignas(16) ushort_t As[2][3][64][32];
  __shared__ alignas(16) u8 Bs8[2][256][32];

  const int tid  = threadIdx.x;
  const int lane = tid & 63;
  const int wave = tid >> 6;
  const int wrow = (wave >> 1) * 16;
  const int wcol = (wave & 1) * 128;
  const int frow = lane & 15;
  const int fsl  = lane >> 4;

  const u8* Bb = x2sT8 + (size_t)tb * N_DIM * C_DIM;

  const int a0p = wave >> 2, a0q = wave & 3;
  const int arl = lane >> 2;
  const int acl = (lane & 3) * 8;
  const int brl = lane >> 1;
  const int bcl = (lane & 1) * 16;
  const int cbx = (wave < 4) ? (4 + wave) : (wave - 4);

#define K5_STAGE(s_) {                                                                     \
    const int kb_ = (s_) * 32; const int bf_ = (s_) & 1;                                   \
    gload16(Sp + (size_t)a0p * 262144 + (size_t)(mloc + a0q * 16 + arl) * 512 + kb_ + acl, \
            &As[bf_][a0p][a0q * 16][0]);                                                   \
    if (wave < 4)                                                                          \
      gload16(Sp + 2 * 262144 + (size_t)(mloc + wave * 16 + arl) * 512 + kb_ + acl,        \
              &As[bf_][2][wave * 16][0]);                                                  \
    gload16(Bb + (size_t)(cbx * 32 + brl) * 512 + kb_ + bcl, &Bs8[bf_][cbx * 32][0]);      \
  }

  f32x4 acc[8];
#pragma unroll
  for (int j = 0; j < 8; j++) acc[j] = (f32x4){0.f, 0.f, 0.f, 0.f};

  K5_STAGE(0);
  __syncthreads();

  for (int s = 0; s < 16; s++) {
    const int cur = s & 1;
    if (s < 15) K5_STAGE(s + 1);

    bf16x8 af[3];
    const int ar = wrow + frow;
#pragma unroll
    for (int p = 0; p < 3; p++) af[p] = *(const bf16x8*)&As[cur][p][ar][fsl * 8];

#pragma unroll
    for (int j = 0; j < 8; j++) {
      const int row = wcol + j * 16 + frow;
      uint2 raw = *(const uint2*)&Bs8[cur][row][fsl * 8];
      union { bf16x8 v; unsigned int u[4]; } bu;
      bu.u[0] = __builtin_amdgcn_perm(0u, raw.x, 0x05010400u) * 0x3F80u;
      bu.u[1] = __builtin_amdgcn_perm(0u, raw.x, 0x07030602u) * 0x3F80u;
      bu.u[2] = __builtin_amdgcn_perm(0u, raw.y, 0x05010400u) * 0x3F80u;
      bu.u[3] = __builtin_amdgcn_perm(0u, raw.y, 0x07030602u) * 0x3F80u;
#pragma unroll
      for (int p = 0; p < 3; p++)
        acc[j] = __builtin_amdgcn_mfma_f32_16x16x32_bf16(af[p], bu.v, acc[j], 0, 0, 0);
    }
    __syncthreads();
  }

  const int crow0 = (lane >> 4) * 4;
  const int cn    = lane & 15;
#pragma unroll
  for (int r = 0; r < 4; r++) {
    const int c = mloc + wrow + crow0 + r;
    const float scf = psc[c];
    const float bif = pbi[c];
    const float bpf = bp[c];
#pragma unroll
    for (int j = 0; j < 8; j++) {
      const int n = wcol + j * 16 + cn;
      const size_t idx = ((size_t)tb * C_DIM + c) * N_DIM + n;
      out0[idx] = (acc[j][r] + bpf) * scf + bif + x[idx];
    }
  }
#undef K5_STAGE
}

// ---------------------------------------------------------------------------
// fp32 problem. d_out = 33,554,432 floats: out0 [0,16.7M), out1 [16.7M,33.5M).
// Scratch in out0 byte region (dead until K5 overwrites it):
//   o0+0    xsT8 16MB [K1->K2]  (aliased by attn 8MB [K3->K4])
//   o0+16M  qs8 16MB [K2->K4] ; o0+32M ks8 16MB [K2->K3]
//   o0+48M  Sqkv split 4.5MB [K0->K2]
// d_ws: x2sT8 16MB [K4->K5]; +16M Sp split 1.5MB [K0->K5].
// ---------------------------------------------------------------------------
extern "C" void kernel_launch(void* const* d_in, const int* in_sizes, int n_in,
                              void* d_out, int out_size, void* d_ws, size_t ws_size,
                              hipStream_t stream) {
  const float* x   = (const float*)d_in[0];
  const float* Wq  = (const float*)d_in[1];
  const float* qsc = (const float*)d_in[2];
  const float* qbi = (const float*)d_in[3];
  const float* Wk  = (const float*)d_in[4];
  const float* ksc = (const float*)d_in[5];
  const float* kbi = (const float*)d_in[6];
  const float* Wv  = (const float*)d_in[7];
  const float* vsc = (const float*)d_in[8];
  const float* vbi = (const float*)d_in[9];
  const float* Wp  = (const float*)d_in[10];
  const float* bp  = (const float*)d_in[11];
  const float* psc = (const float*)d_in[12];
  const float* pbi = (const float*)d_in[13];

  float* out0 = (float*)d_out;
  float* out1 = out0 + 16777216;

  const size_t M16 = 16u * 1024u * 1024u;
  char* o0 = (char*)d_out;
  char* ws = (char*)d_ws;

  u8*       xsT8  = (u8*)(o0);
  u8*       qs8   = (u8*)(o0 + M16);
  u8*       ks8   = (u8*)(o0 + 2 * M16);
  ushort_t* Sqkv  = (ushort_t*)(o0 + 3 * M16);
  float*    attn  = (float*)(o0);
  u8*       x2sT8 = (u8*)(ws);
  ushort_t* Sp    = (ushort_t*)(ws + M16);

  hipLaunchKernelGGL(k0_split,        dim3(512),        dim3(256), 0, stream,
                     Wq, Wk, Wv, Wp, Sqkv, Sp);
  hipLaunchKernelGGL(k1_shortcut_lif, dim3(4, 8, 32),   dim3(256), 0, stream, x, xsT8);
  hipLaunchKernelGGL(k2_qkv,          dim3(24, 32),     dim3(512), 0, stream,
                     xsT8, Sqkv, qsc, qbi, ksc, kbi, vsc, vbi, qs8, ks8, out1);
  hipLaunchKernelGGL(k3_attn,         dim3(8, 32, 2),   dim3(256), 0, stream, ks8, out1, attn);
  hipLaunchKernelGGL(k4_out_lif,      dim3(8, 32, 4),   dim3(256), 0, stream, qs8, attn, x2sT8);
  hipLaunchKernelGGL(k5_proj,         dim3(8, 128),     dim3(512), 0, stream,
                     x2sT8, Sp, bp, psc, pbi, x, out0);
}

// Round 2
// 521.529 us; speedup vs baseline: 1.0388x; 1.0388x over previous
//
#include <hip/hip_runtime.h>

typedef unsigned short ushort_t;
typedef unsigned char u8;
typedef short bf16x8 __attribute__((ext_vector_type(8)));
typedef float f32x4 __attribute__((ext_vector_type(4)));

#define T_DIM 4
#define B_DIM 32
#define C_DIM 512
#define N_DIM 256

__device__ __forceinline__ float bf2f(ushort_t u) {
  union { unsigned int i; float f; } x;
  x.i = ((unsigned int)u) << 16;
  return x.f;
}
__device__ __forceinline__ ushort_t f2bf(float f) {
  unsigned int u = __float_as_uint(f);
  u = (u + 0x7FFFu + ((u >> 16) & 1u)) >> 16;
  return (ushort_t)u;
}

// async global->LDS DMA, 16B per lane, lane i lands at ldsbase + i*16
__device__ __forceinline__ void gload16(const void* g, void* l) {
  __builtin_amdgcn_global_load_lds(
      (const __attribute__((address_space(1))) unsigned int*)g,
      (__attribute__((address_space(3))) unsigned int*)l, 16, 0, 0);
}

// ---------------------------------------------------------------------------
// K0: split fp32 weights into 3 bf16 planes (hi, mid, lo). W ~= hi+mid+lo.
// ---------------------------------------------------------------------------
__global__ __launch_bounds__(256) void k0_split(
    const float* __restrict__ Wq, const float* __restrict__ Wk,
    const float* __restrict__ Wv, const float* __restrict__ Wp,
    ushort_t* __restrict__ Sqkv, ushort_t* __restrict__ Sp)
{
  int gid = blockIdx.x * 256 + threadIdx.x;   // [0, 131072)
  int w = gid >> 15;
  int off = (gid & 32767) * 8;
  const float* src = (w == 0) ? Wq : ((w == 1) ? Wk : ((w == 2) ? Wv : Wp));
  ushort_t* dst = (w < 3) ? (Sqkv + (size_t)w * 3 * 262144) : Sp;
  float wv[8];
  *(float4*)&wv[0] = *(const float4*)(src + off);
  *(float4*)&wv[4] = *(const float4*)(src + off + 4);
  ushort_t hi[8], mi[8], lo[8];
#pragma unroll
  for (int i = 0; i < 8; i++) {
    float f = wv[i];
    ushort_t h = f2bf(f);  float r  = f - bf2f(h);
    ushort_t m = f2bf(r);  float r2 = r - bf2f(m);
    ushort_t l = f2bf(r2);
    hi[i] = h; mi[i] = m; lo[i] = l;
  }
  *(uint4*)(dst + off)              = *(uint4*)&hi[0];
  *(uint4*)(dst + 262144 + off)     = *(uint4*)&mi[0];
  *(uint4*)(dst + 2 * 262144 + off) = *(uint4*)&lo[0];
}

// ---------------------------------------------------------------------------
// K1: shortcut LIF on x [T,B,C,N] (fp32) -> spikes transposed xsT8 [T,B,N,C] u8
// ---------------------------------------------------------------------------
__global__ __launch_bounds__(256) void k1_shortcut_lif(
    const float* __restrict__ x, u8* __restrict__ xsT8)
{
  const int n0 = blockIdx.x * 64;
  const int c0 = blockIdx.y * 64;
  const int b  = blockIdx.z;
  __shared__ u8 sm[64][80];
  const int tid = threadIdx.x;
  const int r  = tid >> 2;
  const int j0 = (tid & 3) * 16;
  float v[16];
#pragma unroll
  for (int i = 0; i < 16; i++) v[i] = 0.f;
  for (int t = 0; t < T_DIM; t++) {
    const float* xp = x + ((((size_t)t * B_DIM + b) * C_DIM) + c0 + r) * N_DIM + n0 + j0;
    float xv[16];
    *(float4*)&xv[0]  = *(const float4*)xp;
    *(float4*)&xv[4]  = *(const float4*)(xp + 4);
    *(float4*)&xv[8]  = *(const float4*)(xp + 8);
    *(float4*)&xv[12] = *(const float4*)(xp + 12);
    __syncthreads();
#pragma unroll
    for (int i = 0; i < 16; i++) {
      float nv = v[i] + (xv[i] - v[i]) * 0.5f;
      bool s = (nv >= 1.0f);
      v[i] = s ? 0.f : nv;
      sm[j0 + i][r] = s ? (u8)1 : (u8)0;
    }
    __syncthreads();
    union { uint4 u; u8 b[16]; } ov;
#pragma unroll
    for (int i = 0; i < 16; i++) ov.b[i] = sm[r][j0 + i];
    u8* op = xsT8 + ((((size_t)t * B_DIM + b) * N_DIM) + n0 + r) * C_DIM + c0 + j0;
    *(uint4*)op = ov.u;
  }
}

// ---------------------------------------------------------------------------
// K2: QKV conv1x1 + BN + LIF. 512 threads (8 waves), 64m x 256n block tile,
// wave tile 16m x 128n (acc[8]). A (3 bf16 planes) and B (spike u8) staged
// via async global_load_lds. LDS dest is linear (DMA constraint); bank-
// conflict-free reads achieved by PRE-SWIZZLING the per-lane global source
// (rule: both-sides-or-neither):
//   A: slot' = slot ^ ((row>>1)&3)  (16B slots; proven 0-conflict pattern)
//   B: slot' = slot ^ (((row>>2)&1)<<1) (8B slots, pair-preserving XOR so a
//      lane's 16B DMA stays contiguous; worst-case 2-way = free)
// B kept as u8 in LDS; expanded to bf16 at frag-read via v_perm_b32 + mul,
// amortized over the 3 A-planes. One barrier per k-step, double-buffered.
// t-loop fused (LIF v-state in regs); epilogue every 16 k-steps.
//    q -> qs8[t,b,c,n] u8 ; k -> ks8[t,b,c,n] u8
//    v -> vout[t,b,h,n,d] fp32 0/1 via full-line float4 stores.
// ---------------------------------------------------------------------------
__global__ __launch_bounds__(512, 4) void k2_qkv(
    const u8* __restrict__ xsT8, const ushort_t* __restrict__ Sqkv,
    const float* __restrict__ qsc, const float* __restrict__ qbi,
    const float* __restrict__ ksc, const float* __restrict__ kbi,
    const float* __restrict__ vsc, const float* __restrict__ vbi,
    u8* __restrict__ qs8, u8* __restrict__ ks8, float* __restrict__ vout)
{
  const int mt = blockIdx.x;          // 0..23
  const int b  = blockIdx.y;          // 0..31
  const int branch = mt >> 3;         // 0=q 1=k 2=v
  const int mloc = (mt & 7) * 64;     // within branch's 512
  const ushort_t* Ws = Sqkv + (size_t)branch * 3 * 262144;
  const float* scp = (branch == 0) ? qsc : ((branch == 1) ? ksc : vsc);
  const float* bip = (branch == 0) ? qbi : ((branch == 1) ? kbi : vbi);

  __shared__ alignas(16) ushort_t As[2][3][64][32];   // 24 KB, linear dest
  __shared__ alignas(16) u8 Bs8[2][256][32];          // 16 KB, linear dest

  const int tid  = threadIdx.x;
  const int lane = tid & 63;
  const int wave = tid >> 6;
  const int wrow = (wave >> 1) * 16;   // m strip (16 rows)
  const int wcol = (wave & 1) * 128;   // n half (128 cols)
  const int frow = lane & 15;
  const int fsl  = lane >> 4;          // 8-elem slot 0..3

  const u8* Bb0 = xsT8 + (size_t)b * N_DIM * C_DIM;

  // staging chunks: 12 A-chunks (1KB = plane p, 16-row group q) over 8 waves,
  // 8 B-chunks (1KB = 32 n-rows). waves 0-3: A{wave}, A{8+wave}, B{4+wave};
  // waves 4-7: A{wave}, B{wave-4}.
  const int a0p = wave >> 2, a0q = wave & 3;
  const int arl = lane >> 2;                              // row within 16
  const int acl = (((lane & 3) ^ ((arl >> 1) & 3)) * 8);  // swizzled 16B slot (ushort units)
  const int brl = lane >> 1;                              // row within 32
  const int bcl = (((lane & 1) ^ ((brl >> 2) & 1)) * 16); // swizzled 16B half (byte units)
  const int cbx = (wave < 4) ? (4 + wave) : (wave - 4);

#define K2_STAGE(s_) {                                                                     \
    const int t_ = (s_) >> 4; const int kb_ = ((s_) & 15) * 32; const int bf_ = (s_) & 1;  \
    gload16(Ws + (size_t)a0p * 262144 + (size_t)(mloc + a0q * 16 + arl) * 512 + kb_ + acl, \
            &As[bf_][a0p][a0q * 16][0]);                                                   \
    if (wave < 4)                                                                          \
      gload16(Ws + 2 * 262144 + (size_t)(mloc + wave * 16 + arl) * 512 + kb_ + acl,        \
              &As[bf_][2][wave * 16][0]);                                                  \
    gload16(Bb0 + (size_t)t_ * (B_DIM * N_DIM * C_DIM) + (size_t)(cbx * 32 + brl) * 512 + kb_ + bcl, \
            &Bs8[bf_][cbx * 32][0]);                                                       \
  }

  f32x4 acc[8];
  float vst[32];
#pragma unroll
  for (int i = 0; i < 32; i++) vst[i] = 0.f;
#pragma unroll
  for (int j = 0; j < 8; j++) acc[j] = (f32x4){0.f, 0.f, 0.f, 0.f};

  // preload BN scale/bias for this thread's 4 c-rows (constant across t)
  const int crow0 = (lane >> 4) * 4;
  const int cn    = lane & 15;
  float sc4[4], bi4[4];
#pragma unroll
  for (int r = 0; r < 4; r++) {
    int c = mloc + wrow + crow0 + r;
    sc4[r] = scp[c]; bi4[r] = bip[c];
  }

  K2_STAGE(0);
  __syncthreads();

  for (int s = 0; s < 64; s++) {
    const int cur = s & 1;
    if (s < 63) K2_STAGE(s + 1);   // async into buf^1, lands during compute

    bf16x8 af[3];
    const int ar = wrow + frow;
    const int asw = (fsl ^ ((ar >> 1) & 3)) * 8;   // matches source pre-swizzle
#pragma unroll
    for (int p = 0; p < 3; p++) af[p] = *(const bf16x8*)&As[cur][p][ar][asw];

#pragma unroll
    for (int j = 0; j < 8; j++) {
      const int row = wcol + j * 16 + frow;
      const int bsw = (fsl ^ (((row >> 2) & 1) << 1)) * 8;  // matches source pre-swizzle
      uint2 raw = *(const uint2*)&Bs8[cur][row][bsw];
      union { bf16x8 v; unsigned int u[4]; } bu;
      bu.u[0] = __builtin_amdgcn_perm(0u, raw.x, 0x05010400u) * 0x3F80u;
      bu.u[1] = __builtin_amdgcn_perm(0u, raw.x, 0x07030602u) * 0x3F80u;
      bu.u[2] = __builtin_amdgcn_perm(0u, raw.y, 0x05010400u) * 0x3F80u;
      bu.u[3] = __builtin_amdgcn_perm(0u, raw.y, 0x07030602u) * 0x3F80u;
#pragma unroll
      for (int p = 0; p < 3; p++)
        acc[j] = __builtin_amdgcn_mfma_f32_16x16x32_bf16(af[p], bu.v, acc[j], 0, 0, 0);
    }

    if ((s & 15) == 15) {
      // epilogue for t = s>>4
      const int t = s >> 4;
      const size_t tb = (size_t)t * B_DIM + b;
      if (branch < 2) {
        u8* dst = (branch == 0) ? qs8 : ks8;
#pragma unroll
        for (int r = 0; r < 4; r++) {
          const int c = mloc + wrow + crow0 + r;
#pragma unroll
          for (int j = 0; j < 8; j++) {
            const int n = wcol + j * 16 + cn;
            float y = acc[j][r] * sc4[r] + bi4[r];
            const int vi = j * 4 + r;
            float v = vst[vi];
            v = v + (y - v) * 0.5f;
            bool sp = (v >= 1.0f);
            vst[vi] = sp ? 0.f : v;
            dst[(tb * C_DIM + c) * N_DIM + n] = sp ? (u8)1 : (u8)0;
          }
        }
      } else {
        const int hv = mloc >> 6;
        const int d0 = wrow + crow0;
#pragma unroll
        for (int j = 0; j < 8; j++) {
          const int n = wcol + j * 16 + cn;
          float ov[4];
#pragma unroll
          for (int r = 0; r < 4; r++) {
            float y = acc[j][r] * sc4[r] + bi4[r];
            const int vi = j * 4 + r;
            float v = vst[vi];
            v = v + (y - v) * 0.5f;
            bool sp = (v >= 1.0f);
            vst[vi] = sp ? 0.f : v;
            ov[r] = sp ? 1.0f : 0.0f;
          }
          *(float4*)(vout + ((tb * 8 + hv) * N_DIM + n) * 64 + d0) =
              make_float4(ov[0], ov[1], ov[2], ov[3]);
        }
      }
#pragma unroll
      for (int j = 0; j < 8; j++) acc[j] = (f32x4){0.f, 0.f, 0.f, 0.f};
    }
    __syncthreads();
  }
#undef K2_STAGE
}

// ---------------------------------------------------------------------------
// K3: attn[ch,b,h,d,e] = (1/16) * sum_{t,n} k[d,(t,n)] * v[(t,n),e]
// ---------------------------------------------------------------------------
__global__ __launch_bounds__(256) void k3_attn(
    const u8* __restrict__ ks8, const float* __restrict__ vsp,
    float* __restrict__ attn)
{
  const int h  = blockIdx.x;
  const int b  = blockIdx.y;
  const int ch = blockIdx.z;
  __shared__ u8 KtT[64][80];
  __shared__ u8 Vt[64][80];
  const int tid = threadIdx.x;
  const int d0 = (tid >> 4) * 4;
  const int e0 = (tid & 15) * 4;
  float a[16];
#pragma unroll
  for (int i = 0; i < 16; i++) a[i] = 0.f;

  for (int tt = 0; tt < 2; tt++) {
    int t = ch * 2 + tt;
    for (int n0 = 0; n0 < 256; n0 += 64) {
      __syncthreads();
      {
        int d  = tid >> 2;
        int s0 = (tid & 3) * 16;
        union { uint4 u; u8 bvec[16]; } kb;
        kb.u = *(const uint4*)(ks8 + ((((size_t)t * B_DIM + b) * C_DIM) + h * 64 + d) * N_DIM + n0 + s0);
#pragma unroll
        for (int i = 0; i < 16; i++) KtT[s0 + i][d] = kb.bvec[i];
      }
      {
        const float* vb = vsp + ((((size_t)t * B_DIM + b) * 8 + h) * N_DIM + n0) * 64;
#pragma unroll
        for (int u = 0; u < 4; u++) {
          int chunk = tid + u * 256;
          int row = chunk >> 4;
          int eo  = (chunk & 15) * 4;
          float4 v4 = *(const float4*)(vb + (size_t)row * 64 + eo);
          Vt[row][eo + 0] = (u8)(v4.x != 0.f);
          Vt[row][eo + 1] = (u8)(v4.y != 0.f);
          Vt[row][eo + 2] = (u8)(v4.z != 0.f);
          Vt[row][eo + 3] = (u8)(v4.w != 0.f);
        }
      }
      __syncthreads();
      for (int s = 0; s < 64; s++) {
        uchar4 kb = *(const uchar4*)&KtT[s][d0];
        float kv[4] = { (float)kb.x, (float)kb.y, (float)kb.z, (float)kb.w };
        uchar4 vr = *(const uchar4*)&Vt[s][e0];
        float vv[4] = { (float)vr.x, (float)vr.y, (float)vr.z, (float)vr.w };
#pragma unroll
        for (int i = 0; i < 4; i++)
#pragma unroll
          for (int j = 0; j < 4; j++) a[i * 4 + j] += kv[i] * vv[j];
      }
    }
  }
  float* ap = attn + ((((size_t)ch * B_DIM + b) * 8 + h) * 64 + d0) * 64 + e0;
#pragma unroll
  for (int i = 0; i < 4; i++)
#pragma unroll
    for (int j = 0; j < 4; j++)
      ap[i * 64 + j] = a[i * 4 + j] * 0.0625f;
}

// ---------------------------------------------------------------------------
// K4: out[e,n] = sum_d attn[d,e]*q[d,n], attn-LIF(0.5) -> x2sT8[t,b,n,c] u8.
// n-chunk split across grid.z for 4x parallelism; vst[16] per thread.
// ---------------------------------------------------------------------------
__global__ __launch_bounds__(256) void k4_out_lif(
    const u8* __restrict__ qs8, const float* __restrict__ attn,
    u8* __restrict__ x2sT8)
{
  const int h  = blockIdx.x;
  const int b  = blockIdx.y;
  const int nc = blockIdx.z;   // 0..3
  __shared__ float At[64][68];
  __shared__ u8 Qt[64][80];
  const int tid = threadIdx.x;
  const int e0 = (tid >> 4) * 4;
  const int n0 = (tid & 15) * 4;
  float vst[16];
#pragma unroll
  for (int i = 0; i < 16; i++) vst[i] = 0.f;

  for (int t = 0; t < T_DIM; t++) {
    if ((t & 1) == 0) {
      __syncthreads();
      const float* ap = attn + ((((size_t)(t >> 1) * B_DIM + b) * 8) + h) * 4096;
      int dr = tid >> 2;
      int co = (tid & 3) * 16;
#pragma unroll
      for (int u = 0; u < 4; u++)
        *(float4*)&At[dr][co + u * 4] = *(const float4*)(ap + dr * 64 + co + u * 4);
    }
    __syncthreads();
    {
      int d  = tid >> 2;
      int so = (tid & 3) * 16;
      *(uint4*)&Qt[d][so] =
        *(const uint4*)(qs8 + ((((size_t)t * B_DIM + b) * C_DIM) + h * 64 + d) * N_DIM + nc * 64 + so);
    }
    __syncthreads();
    float acc[16];
#pragma unroll
    for (int i = 0; i < 16; i++) acc[i] = 0.f;
    for (int d = 0; d < 64; d++) {
      float4 av = *(const float4*)&At[d][e0];
      float avv[4] = { av.x, av.y, av.z, av.w };
      uchar4 qr = *(const uchar4*)&Qt[d][n0];
      float qv[4] = { (float)qr.x, (float)qr.y, (float)qr.z, (float)qr.w };
#pragma unroll
      for (int i = 0; i < 4; i++)
#pragma unroll
        for (int j = 0; j < 4; j++) acc[i * 4 + j] += avv[i] * qv[j];
    }
#pragma unroll
    for (int j = 0; j < 4; j++) {
      u8 sv[4];
#pragma unroll
      for (int i = 0; i < 4; i++) {
        int vi = i * 4 + j;
        float y = acc[i * 4 + j];
        float nv = vst[vi] + (y - vst[vi]) * 0.5f;
        bool s = (nv >= 0.5f);
        vst[vi] = s ? 0.f : nv;
        sv[i] = s ? (u8)1 : (u8)0;
      }
      int n = nc * 64 + n0 + j;
      u8* op = x2sT8 + ((((size_t)t * B_DIM + b) * N_DIM) + n) * C_DIM + h * 64 + e0;
      *(uchar4*)op = make_uchar4(sv[0], sv[1], sv[2], sv[3]);
    }
  }
}

// ---------------------------------------------------------------------------
// K5: proj conv1x1 (+bp)*scale+bias + residual -> out0 fp32. Same engine as
// K2: 64m x 256n block, wave 16x128, async global_load_lds staging with
// pre-swizzled sources, u8 B in LDS with read-time bf16 expansion.
// ---------------------------------------------------------------------------
__global__ __launch_bounds__(512, 4) void k5_proj(
    const u8* __restrict__ x2sT8, const ushort_t* __restrict__ Sp,
    const float* __restrict__ bp, const float* __restrict__ psc,
    const float* __restrict__ pbi,
    const float* __restrict__ x, float* __restrict__ out0)
{
  const int mt = blockIdx.x;   // 0..7
  const int tb = blockIdx.y;   // 0..127
  const int mloc = mt * 64;

  __shared__ alignas(16) ushort_t As[2][3][64][32];
  __shared__ alignas(16) u8 Bs8[2][256][32];

  const int tid  = threadIdx.x;
  const int lane = tid & 63;
  const int wave = tid >> 6;
  const int wrow = (wave >> 1) * 16;
  const int wcol = (wave & 1) * 128;
  const int frow = lane & 15;
  const int fsl  = lane >> 4;

  const u8* Bb = x2sT8 + (size_t)tb * N_DIM * C_DIM;

  const int a0p = wave >> 2, a0q = wave & 3;
  const int arl = lane >> 2;
  const int acl = (((lane & 3) ^ ((arl >> 1) & 3)) * 8);
  const int brl = lane >> 1;
  const int bcl = (((lane & 1) ^ ((brl >> 2) & 1)) * 16);
  const int cbx = (wave < 4) ? (4 + wave) : (wave - 4);

#define K5_STAGE(s_) {                                                                     \
    const int kb_ = (s_) * 32; const int bf_ = (s_) & 1;                                   \
    gload16(Sp + (size_t)a0p * 262144 + (size_t)(mloc + a0q * 16 + arl) * 512 + kb_ + acl, \
            &As[bf_][a0p][a0q * 16][0]);                                                   \
    if (wave < 4)                                                                          \
      gload16(Sp + 2 * 262144 + (size_t)(mloc + wave * 16 + arl) * 512 + kb_ + acl,        \
              &As[bf_][2][wave * 16][0]);                                                  \
    gload16(Bb + (size_t)(cbx * 32 + brl) * 512 + kb_ + bcl, &Bs8[bf_][cbx * 32][0]);      \
  }

  f32x4 acc[8];
#pragma unroll
  for (int j = 0; j < 8; j++) acc[j] = (f32x4){0.f, 0.f, 0.f, 0.f};

  K5_STAGE(0);
  __syncthreads();

  for (int s = 0; s < 16; s++) {
    const int cur = s & 1;
    if (s < 15) K5_STAGE(s + 1);

    bf16x8 af[3];
    const int ar = wrow + frow;
    const int asw = (fsl ^ ((ar >> 1) & 3)) * 8;
#pragma unroll
    for (int p = 0; p < 3; p++) af[p] = *(const bf16x8*)&As[cur][p][ar][asw];

#pragma unroll
    for (int j = 0; j < 8; j++) {
      const int row = wcol + j * 16 + frow;
      const int bsw = (fsl ^ (((row >> 2) & 1) << 1)) * 8;
      uint2 raw = *(const uint2*)&Bs8[cur][row][bsw];
      union { bf16x8 v; unsigned int u[4]; } bu;
      bu.u[0] = __builtin_amdgcn_perm(0u, raw.x, 0x05010400u) * 0x3F80u;
      bu.u[1] = __builtin_amdgcn_perm(0u, raw.x, 0x07030602u) * 0x3F80u;
      bu.u[2] = __builtin_amdgcn_perm(0u, raw.y, 0x05010400u) * 0x3F80u;
      bu.u[3] = __builtin_amdgcn_perm(0u, raw.y, 0x07030602u) * 0x3F80u;
#pragma unroll
      for (int p = 0; p < 3; p++)
        acc[j] = __builtin_amdgcn_mfma_f32_16x16x32_bf16(af[p], bu.v, acc[j], 0, 0, 0);
    }
    __syncthreads();
  }

  const int crow0 = (lane >> 4) * 4;
  const int cn    = lane & 15;
#pragma unroll
  for (int r = 0; r < 4; r++) {
    const int c = mloc + wrow + crow0 + r;
    const float scf = psc[c];
    const float bif = pbi[c];
    const float bpf = bp[c];
#pragma unroll
    for (int j = 0; j < 8; j++) {
      const int n = wcol + j * 16 + cn;
      const size_t idx = ((size_t)tb * C_DIM + c) * N_DIM + n;
      out0[idx] = (acc[j][r] + bpf) * scf + bif + x[idx];
    }
  }
#undef K5_STAGE
}

// ---------------------------------------------------------------------------
// fp32 problem. d_out = 33,554,432 floats: out0 [0,16.7M), out1 [16.7M,33.5M).
// Scratch in out0 byte region (dead until K5 overwrites it):
//   o0+0    xsT8 16MB [K1->K2]  (aliased by attn 8MB [K3->K4])
//   o0+16M  qs8 16MB [K2->K4] ; o0+32M ks8 16MB [K2->K3]
//   o0+48M  Sqkv split 4.5MB [K0->K2]
// d_ws: x2sT8 16MB [K4->K5]; +16M Sp split 1.5MB [K0->K5].
// ---------------------------------------------------------------------------
extern "C" void kernel_launch(void* const* d_in, const int* in_sizes, int n_in,
                              void* d_out, int out_size, void* d_ws, size_t ws_size,
                              hipStream_t stream) {
  const float* x   = (const float*)d_in[0];
  const float* Wq  = (const float*)d_in[1];
  const float* qsc = (const float*)d_in[2];
  const float* qbi = (const float*)d_in[3];
  const float* Wk  = (const float*)d_in[4];
  const float* ksc = (const float*)d_in[5];
  const float* kbi = (const float*)d_in[6];
  const float* Wv  = (const float*)d_in[7];
  const float* vsc = (const float*)d_in[8];
  const float* vbi = (const float*)d_in[9];
  const float* Wp  = (const float*)d_in[10];
  const float* bp  = (const float*)d_in[11];
  const float* psc = (const float*)d_in[12];
  const float* pbi = (const float*)d_in[13];

  float* out0 = (float*)d_out;
  float* out1 = out0 + 16777216;

  const size_t M16 = 16u * 1024u * 1024u;
  char* o0 = (char*)d_out;
  char* ws = (char*)d_ws;

  u8*       xsT8  = (u8*)(o0);
  u8*       qs8   = (u8*)(o0 + M16);
  u8*       ks8   = (u8*)(o0 + 2 * M16);
  ushort_t* Sqkv  = (ushort_t*)(o0 + 3 * M16);
  float*    attn  = (float*)(o0);
  u8*       x2sT8 = (u8*)(ws);
  ushort_t* Sp    = (ushort_t*)(ws + M16);

  hipLaunchKernelGGL(k0_split,        dim3(512),        dim3(256), 0, stream,
                     Wq, Wk, Wv, Wp, Sqkv, Sp);
  hipLaunchKernelGGL(k1_shortcut_lif, dim3(4, 8, 32),   dim3(256), 0, stream, x, xsT8);
  hipLaunchKernelGGL(k2_qkv,          dim3(24, 32),     dim3(512), 0, stream,
                     xsT8, Sqkv, qsc, qbi, ksc, kbi, vsc, vbi, qs8, ks8, out1);
  hipLaunchKernelGGL(k3_attn,         dim3(8, 32, 2),   dim3(256), 0, stream, ks8, out1, attn);
  hipLaunchKernelGGL(k4_out_lif,      dim3(8, 32, 4),   dim3(256), 0, stream, qs8, attn, x2sT8);
  hipLaunchKernelGGL(k5_proj,         dim3(8, 128),     dim3(512), 0, stream,
                     x2sT8, Sp, bp, psc, pbi, x, out0);
}

// Round 3
// 494.655 us; speedup vs baseline: 1.0952x; 1.0543x over previous
//
#include <hip/hip_runtime.h>

typedef unsigned short ushort_t;
typedef unsigned char u8;
typedef short bf16x8 __attribute__((ext_vector_type(8)));
typedef float f32x4 __attribute__((ext_vector_type(4)));

#define T_DIM 4
#define B_DIM 32
#define C_DIM 512
#define N_DIM 256

__device__ __forceinline__ float bf2f(ushort_t u) {
  union { unsigned int i; float f; } x;
  x.i = ((unsigned int)u) << 16;
  return x.f;
}
__device__ __forceinline__ ushort_t f2bf(float f) {
  unsigned int u = __float_as_uint(f);
  u = (u + 0x7FFFu + ((u >> 16) & 1u)) >> 16;
  return (ushort_t)u;
}

// async global->LDS DMA, 16B per lane, lane i lands at ldsbase + i*16
__device__ __forceinline__ void gload16(const void* g, void* l) {
  __builtin_amdgcn_global_load_lds(
      (const __attribute__((address_space(1))) unsigned int*)g,
      (__attribute__((address_space(3))) unsigned int*)l, 16, 0, 0);
}

// ---------------------------------------------------------------------------
// K0: split fp32 weights into 3 bf16 planes (hi, mid, lo). W ~= hi+mid+lo.
// ---------------------------------------------------------------------------
__global__ __launch_bounds__(256) void k0_split(
    const float* __restrict__ Wq, const float* __restrict__ Wk,
    const float* __restrict__ Wv, const float* __restrict__ Wp,
    ushort_t* __restrict__ Sqkv, ushort_t* __restrict__ Sp)
{
  int gid = blockIdx.x * 256 + threadIdx.x;   // [0, 131072)
  int w = gid >> 15;
  int off = (gid & 32767) * 8;
  const float* src = (w == 0) ? Wq : ((w == 1) ? Wk : ((w == 2) ? Wv : Wp));
  ushort_t* dst = (w < 3) ? (Sqkv + (size_t)w * 3 * 262144) : Sp;
  float wv[8];
  *(float4*)&wv[0] = *(const float4*)(src + off);
  *(float4*)&wv[4] = *(const float4*)(src + off + 4);
  ushort_t hi[8], mi[8], lo[8];
#pragma unroll
  for (int i = 0; i < 8; i++) {
    float f = wv[i];
    ushort_t h = f2bf(f);  float r  = f - bf2f(h);
    ushort_t m = f2bf(r);  float r2 = r - bf2f(m);
    ushort_t l = f2bf(r2);
    hi[i] = h; mi[i] = m; lo[i] = l;
  }
  *(uint4*)(dst + off)              = *(uint4*)&hi[0];
  *(uint4*)(dst + 262144 + off)     = *(uint4*)&mi[0];
  *(uint4*)(dst + 2 * 262144 + off) = *(uint4*)&lo[0];
}

// ---------------------------------------------------------------------------
// K1: shortcut LIF on x [T,B,C,N] (fp32) -> spikes transposed xsT8 [T,B,N,C] u8
// ---------------------------------------------------------------------------
__global__ __launch_bounds__(256) void k1_shortcut_lif(
    const float* __restrict__ x, u8* __restrict__ xsT8)
{
  const int n0 = blockIdx.x * 64;
  const int c0 = blockIdx.y * 64;
  const int b  = blockIdx.z;
  __shared__ u8 sm[64][80];
  const int tid = threadIdx.x;
  const int r  = tid >> 2;
  const int j0 = (tid & 3) * 16;
  float v[16];
#pragma unroll
  for (int i = 0; i < 16; i++) v[i] = 0.f;
  for (int t = 0; t < T_DIM; t++) {
    const float* xp = x + ((((size_t)t * B_DIM + b) * C_DIM) + c0 + r) * N_DIM + n0 + j0;
    float xv[16];
    *(float4*)&xv[0]  = *(const float4*)xp;
    *(float4*)&xv[4]  = *(const float4*)(xp + 4);
    *(float4*)&xv[8]  = *(const float4*)(xp + 8);
    *(float4*)&xv[12] = *(const float4*)(xp + 12);
    __syncthreads();
#pragma unroll
    for (int i = 0; i < 16; i++) {
      float nv = v[i] + (xv[i] - v[i]) * 0.5f;
      bool s = (nv >= 1.0f);
      v[i] = s ? 0.f : nv;
      sm[j0 + i][r] = s ? (u8)1 : (u8)0;
    }
    __syncthreads();
    union { uint4 u; u8 b[16]; } ov;
#pragma unroll
    for (int i = 0; i < 16; i++) ov.b[i] = sm[r][j0 + i];
    u8* op = xsT8 + ((((size_t)t * B_DIM + b) * N_DIM) + n0 + r) * C_DIM + c0 + j0;
    *(uint4*)op = ov.u;
  }
}

// ---------------------------------------------------------------------------
// K2: QKV conv1x1 + BN + LIF. 512 threads (8 waves), 64m x 256n block tile,
// wave tile 16m x 128n (acc[8]). Counted-vmcnt pipeline (T3/T4):
//   4 rotating LDS buffers (80 KB), prefetch depth 2, ONE raw s_barrier per
//   k-step, s_waitcnt vmcnt(2L) (never 0 in steady state) so stages s+1/s+2
//   stay in flight across the barrier. NB(4) >= P(2)+2 => no buffer race
//   under the 1-step barrier skew.
// A (3 bf16 planes) and B (spike u8) staged via async global_load_lds with
// PRE-SWIZZLED global sources (LDS dest linear), read with matching XOR:
//   A: slot' = slot ^ ((row>>1)&3)   B: slot' = slot ^ (((row>>2)&1)<<1)
// XCD remap: lin%8 == b%8 so each XCD serves 4 b-values; B working set
// 2 MB < 4 MB XCD-L2 -> B fetched once per XCD group.
//    q -> qs8[t,b,c,n] u8 ; k -> ks8[t,b,c,n] u8
//    v -> vout[t,b,h,n,d] fp32 0/1 via full-line float4 stores.
// ---------------------------------------------------------------------------
__global__ __launch_bounds__(512, 4) void k2_qkv(
    const u8* __restrict__ xsT8, const ushort_t* __restrict__ Sqkv,
    const float* __restrict__ qsc, const float* __restrict__ qbi,
    const float* __restrict__ ksc, const float* __restrict__ kbi,
    const float* __restrict__ vsc, const float* __restrict__ vbi,
    u8* __restrict__ qs8, u8* __restrict__ ks8, float* __restrict__ vout)
{
  const int lin = blockIdx.x + blockIdx.y * 24;        // 0..767
  const int b   = (lin & 7) | (((lin >> 3) & 3) << 3); // XCD = lin%8 = b%8
  const int mt  = lin >> 5;                            // 0..23
  const int branch = mt >> 3;         // 0=q 1=k 2=v
  const int mloc = (mt & 7) * 64;     // within branch's 512
  const ushort_t* Ws = Sqkv + (size_t)branch * 3 * 262144;
  const float* scp = (branch == 0) ? qsc : ((branch == 1) ? ksc : vsc);
  const float* bip = (branch == 0) ? qbi : ((branch == 1) ? kbi : vbi);

  __shared__ alignas(16) ushort_t As[4][3][64][32];   // 48 KB, linear dest
  __shared__ alignas(16) u8 Bs8[4][256][32];          // 32 KB, linear dest

  const int tid  = threadIdx.x;
  const int lane = tid & 63;
  const int wave = tid >> 6;
  const int wrow = (wave >> 1) * 16;   // m strip (16 rows)
  const int wcol = (wave & 1) * 128;   // n half (128 cols)
  const int frow = lane & 15;
  const int fsl  = lane >> 4;          // 8-elem slot 0..3

  const u8* Bb0 = xsT8 + (size_t)b * N_DIM * C_DIM;

  // staging chunks: 12 A-chunks (1KB = plane p, 16-row group q) over 8 waves,
  // 8 B-chunks (1KB = 32 n-rows). waves 0-3: A{wave}, A{8+wave}, B{4+wave}
  // (L=3); waves 4-7: A{wave}, B{wave-4} (L=2).
  const int a0p = wave >> 2, a0q = wave & 3;
  const int arl = lane >> 2;                              // row within 16
  const int acl = (((lane & 3) ^ ((arl >> 1) & 3)) * 8);  // swizzled 16B slot (ushort units)
  const int brl = lane >> 1;                              // row within 32
  const int bcl = (((lane & 1) ^ ((brl >> 2) & 1)) * 16); // swizzled 16B half (byte units)
  const int cbx = (wave < 4) ? (4 + wave) : (wave - 4);

#define K2_STAGE(s_) {                                                                     \
    const int ss_ = (s_);                                                                  \
    const int t_ = ss_ >> 4; const int kb_ = (ss_ & 15) * 32; const int bf_ = ss_ & 3;     \
    gload16(Ws + (size_t)a0p * 262144 + (size_t)(mloc + a0q * 16 + arl) * 512 + kb_ + acl, \
            &As[bf_][a0p][a0q * 16][0]);                                                   \
    if (wave < 4)                                                                          \
      gload16(Ws + 2 * 262144 + (size_t)(mloc + wave * 16 + arl) * 512 + kb_ + acl,        \
              &As[bf_][2][wave * 16][0]);                                                  \
    gload16(Bb0 + (size_t)t_ * (B_DIM * N_DIM * C_DIM) + (size_t)(cbx * 32 + brl) * 512 + kb_ + bcl, \
            &Bs8[bf_][cbx * 32][0]);                                                       \
  }

  f32x4 acc[8];
  float vst[32];
#pragma unroll
  for (int i = 0; i < 32; i++) vst[i] = 0.f;
#pragma unroll
  for (int j = 0; j < 8; j++) acc[j] = (f32x4){0.f, 0.f, 0.f, 0.f};

  // preload BN scale/bias for this thread's 4 c-rows (constant across t)
  const int crow0 = (lane >> 4) * 4;
  const int cn    = lane & 15;
  float sc4[4], bi4[4];
#pragma unroll
  for (int r = 0; r < 4; r++) {
    int c = mloc + wrow + crow0 + r;
    sc4[r] = scp[c]; bi4[r] = bip[c];
  }

  K2_STAGE(0);
  K2_STAGE(1);

  for (int s = 0; s < 64; s++) {
    const int cur = s & 3;
    if (s < 62) K2_STAGE(s + 2);   // issue depth-2 prefetch into buf (s+2)&3

    // wait for stage s only: after issuing s+2, outstanding = 3L; keep 2L in
    // flight. Tail: s==62 -> keep L; s==63 -> drain. Per-wave L differs.
    if (s < 62) {
      if (wave < 4) asm volatile("s_waitcnt vmcnt(6)" ::: "memory");
      else          asm volatile("s_waitcnt vmcnt(4)" ::: "memory");
    } else if (s == 62) {
      if (wave < 4) asm volatile("s_waitcnt vmcnt(3)" ::: "memory");
      else          asm volatile("s_waitcnt vmcnt(2)" ::: "memory");
    } else {
      asm volatile("s_waitcnt vmcnt(0)" ::: "memory");
    }
    __builtin_amdgcn_s_barrier();
    __builtin_amdgcn_sched_barrier(0);

    bf16x8 af[3];
    const int ar = wrow + frow;
    const int asw = (fsl ^ ((ar >> 1) & 3)) * 8;   // matches source pre-swizzle
#pragma unroll
    for (int p = 0; p < 3; p++) af[p] = *(const bf16x8*)&As[cur][p][ar][asw];

#pragma unroll
    for (int j = 0; j < 8; j++) {
      const int row = wcol + j * 16 + frow;
      const int bsw = (fsl ^ (((row >> 2) & 1) << 1)) * 8;  // matches source pre-swizzle
      uint2 raw = *(const uint2*)&Bs8[cur][row][bsw];
      union { bf16x8 v; unsigned int u[4]; } bu;
      bu.u[0] = __builtin_amdgcn_perm(0u, raw.x, 0x05010400u) * 0x3F80u;
      bu.u[1] = __builtin_amdgcn_perm(0u, raw.x, 0x07030602u) * 0x3F80u;
      bu.u[2] = __builtin_amdgcn_perm(0u, raw.y, 0x05010400u) * 0x3F80u;
      bu.u[3] = __builtin_amdgcn_perm(0u, raw.y, 0x07030602u) * 0x3F80u;
#pragma unroll
      for (int p = 0; p < 3; p++)
        acc[j] = __builtin_amdgcn_mfma_f32_16x16x32_bf16(af[p], bu.v, acc[j], 0, 0, 0);
    }

    if ((s & 15) == 15) {
      // epilogue for t = s>>4 (stores enter vmcnt FIFO; the next steady-state
      // vmcnt(2L) wait retires them - slightly conservative, still correct)
      const int t = s >> 4;
      const size_t tb = (size_t)t * B_DIM + b;
      if (branch < 2) {
        u8* dst = (branch == 0) ? qs8 : ks8;
#pragma unroll
        for (int r = 0; r < 4; r++) {
          const int c = mloc + wrow + crow0 + r;
#pragma unroll
          for (int j = 0; j < 8; j++) {
            const int n = wcol + j * 16 + cn;
            float y = acc[j][r] * sc4[r] + bi4[r];
            const int vi = j * 4 + r;
            float v = vst[vi];
            v = v + (y - v) * 0.5f;
            bool sp = (v >= 1.0f);
            vst[vi] = sp ? 0.f : v;
            dst[(tb * C_DIM + c) * N_DIM + n] = sp ? (u8)1 : (u8)0;
          }
        }
      } else {
        const int hv = mloc >> 6;
        const int d0 = wrow + crow0;
#pragma unroll
        for (int j = 0; j < 8; j++) {
          const int n = wcol + j * 16 + cn;
          float ov[4];
#pragma unroll
          for (int r = 0; r < 4; r++) {
            float y = acc[j][r] * sc4[r] + bi4[r];
            const int vi = j * 4 + r;
            float v = vst[vi];
            v = v + (y - v) * 0.5f;
            bool sp = (v >= 1.0f);
            vst[vi] = sp ? 0.f : v;
            ov[r] = sp ? 1.0f : 0.0f;
          }
          *(float4*)(vout + ((tb * 8 + hv) * N_DIM + n) * 64 + d0) =
              make_float4(ov[0], ov[1], ov[2], ov[3]);
        }
      }
#pragma unroll
      for (int j = 0; j < 8; j++) acc[j] = (f32x4){0.f, 0.f, 0.f, 0.f};
    }
  }
#undef K2_STAGE
}

// ---------------------------------------------------------------------------
// K3: attn[ch,b,h,d,e] = (1/16) * sum_{t,n} k[d,(t,n)] * v[(t,n),e]
// ---------------------------------------------------------------------------
__global__ __launch_bounds__(256) void k3_attn(
    const u8* __restrict__ ks8, const float* __restrict__ vsp,
    float* __restrict__ attn)
{
  const int h  = blockIdx.x;
  const int b  = blockIdx.y;
  const int ch = blockIdx.z;
  __shared__ u8 KtT[64][80];
  __shared__ u8 Vt[64][80];
  const int tid = threadIdx.x;
  const int d0 = (tid >> 4) * 4;
  const int e0 = (tid & 15) * 4;
  float a[16];
#pragma unroll
  for (int i = 0; i < 16; i++) a[i] = 0.f;

  for (int tt = 0; tt < 2; tt++) {
    int t = ch * 2 + tt;
    for (int n0 = 0; n0 < 256; n0 += 64) {
      __syncthreads();
      {
        int d  = tid >> 2;
        int s0 = (tid & 3) * 16;
        union { uint4 u; u8 bvec[16]; } kb;
        kb.u = *(const uint4*)(ks8 + ((((size_t)t * B_DIM + b) * C_DIM) + h * 64 + d) * N_DIM + n0 + s0);
#pragma unroll
        for (int i = 0; i < 16; i++) KtT[s0 + i][d] = kb.bvec[i];
      }
      {
        const float* vb = vsp + ((((size_t)t * B_DIM + b) * 8 + h) * N_DIM + n0) * 64;
#pragma unroll
        for (int u = 0; u < 4; u++) {
          int chunk = tid + u * 256;
          int row = chunk >> 4;
          int eo  = (chunk & 15) * 4;
          float4 v4 = *(const float4*)(vb + (size_t)row * 64 + eo);
          Vt[row][eo + 0] = (u8)(v4.x != 0.f);
          Vt[row][eo + 1] = (u8)(v4.y != 0.f);
          Vt[row][eo + 2] = (u8)(v4.z != 0.f);
          Vt[row][eo + 3] = (u8)(v4.w != 0.f);
        }
      }
      __syncthreads();
      for (int s = 0; s < 64; s++) {
        uchar4 kb = *(const uchar4*)&KtT[s][d0];
        float kv[4] = { (float)kb.x, (float)kb.y, (float)kb.z, (float)kb.w };
        uchar4 vr = *(const uchar4*)&Vt[s][e0];
        float vv[4] = { (float)vr.x, (float)vr.y, (float)vr.z, (float)vr.w };
#pragma unroll
        for (int i = 0; i < 4; i++)
#pragma unroll
          for (int j = 0; j < 4; j++) a[i * 4 + j] += kv[i] * vv[j];
      }
    }
  }
  float* ap = attn + ((((size_t)ch * B_DIM + b) * 8 + h) * 64 + d0) * 64 + e0;
#pragma unroll
  for (int i = 0; i < 4; i++)
#pragma unroll
    for (int j = 0; j < 4; j++)
      ap[i * 64 + j] = a[i * 4 + j] * 0.0625f;
}

// ---------------------------------------------------------------------------
// K4: out[e,n] = sum_d attn[d,e]*q[d,n], attn-LIF(0.5) -> x2sT8[t,b,n,c] u8.
// n-chunk split across grid.z for 4x parallelism; vst[16] per thread.
// ---------------------------------------------------------------------------
__global__ __launch_bounds__(256) void k4_out_lif(
    const u8* __restrict__ qs8, const float* __restrict__ attn,
    u8* __restrict__ x2sT8)
{
  const int h  = blockIdx.x;
  const int b  = blockIdx.y;
  const int nc = blockIdx.z;   // 0..3
  __shared__ float At[64][68];
  __shared__ u8 Qt[64][80];
  const int tid = threadIdx.x;
  const int e0 = (tid >> 4) * 4;
  const int n0 = (tid & 15) * 4;
  float vst[16];
#pragma unroll
  for (int i = 0; i < 16; i++) vst[i] = 0.f;

  for (int t = 0; t < T_DIM; t++) {
    if ((t & 1) == 0) {
      __syncthreads();
      const float* ap = attn + ((((size_t)(t >> 1) * B_DIM + b) * 8) + h) * 4096;
      int dr = tid >> 2;
      int co = (tid & 3) * 16;
#pragma unroll
      for (int u = 0; u < 4; u++)
        *(float4*)&At[dr][co + u * 4] = *(const float4*)(ap + dr * 64 + co + u * 4);
    }
    __syncthreads();
    {
      int d  = tid >> 2;
      int so = (tid & 3) * 16;
      *(uint4*)&Qt[d][so] =
        *(const uint4*)(qs8 + ((((size_t)t * B_DIM + b) * C_DIM) + h * 64 + d) * N_DIM + nc * 64 + so);
    }
    __syncthreads();
    float acc[16];
#pragma unroll
    for (int i = 0; i < 16; i++) acc[i] = 0.f;
    for (int d = 0; d < 64; d++) {
      float4 av = *(const float4*)&At[d][e0];
      float avv[4] = { av.x, av.y, av.z, av.w };
      uchar4 qr = *(const uchar4*)&Qt[d][n0];
      float qv[4] = { (float)qr.x, (float)qr.y, (float)qr.z, (float)qr.w };
#pragma unroll
      for (int i = 0; i < 4; i++)
#pragma unroll
        for (int j = 0; j < 4; j++) acc[i * 4 + j] += avv[i] * qv[j];
    }
#pragma unroll
    for (int j = 0; j < 4; j++) {
      u8 sv[4];
#pragma unroll
      for (int i = 0; i < 4; i++) {
        int vi = i * 4 + j;
        float y = acc[i * 4 + j];
        float nv = vst[vi] + (y - vst[vi]) * 0.5f;
        bool s = (nv >= 0.5f);
        vst[vi] = s ? 0.f : nv;
        sv[i] = s ? (u8)1 : (u8)0;
      }
      int n = nc * 64 + n0 + j;
      u8* op = x2sT8 + ((((size_t)t * B_DIM + b) * N_DIM) + n) * C_DIM + h * 64 + e0;
      *(uchar4*)op = make_uchar4(sv[0], sv[1], sv[2], sv[3]);
    }
  }
}

// ---------------------------------------------------------------------------
// K5: proj conv1x1 (+bp)*scale+bias + residual -> out0 fp32. Same engine as
// K2: counted-vmcnt depth-2 pipeline, 4 LDS buffers, raw barriers, DMA
// staging with pre-swizzled sources. Grid transposed to (tb, mt) so
// lin%8 = tb%8 -> per-XCD B working set 2 MB (L2-cached).
// ---------------------------------------------------------------------------
__global__ __launch_bounds__(512, 4) void k5_proj(
    const u8* __restrict__ x2sT8, const ushort_t* __restrict__ Sp,
    const float* __restrict__ bp, const float* __restrict__ psc,
    const float* __restrict__ pbi,
    const float* __restrict__ x, float* __restrict__ out0)
{
  const int tb = blockIdx.x;   // 0..127 (fast dim -> XCD = tb%8)
  const int mt = blockIdx.y;   // 0..7
  const int mloc = mt * 64;

  __shared__ alignas(16) ushort_t As[4][3][64][32];
  __shared__ alignas(16) u8 Bs8[4][256][32];

  const int tid  = threadIdx.x;
  const int lane = tid & 63;
  const int wave = tid >> 6;
  const int wrow = (wave >> 1) * 16;
  const int wcol = (wave & 1) * 128;
  const int frow = lane & 15;
  const int fsl  = lane >> 4;

  const u8* Bb = x2sT8 + (size_t)tb * N_DIM * C_DIM;

  const int a0p = wave >> 2, a0q = wave & 3;
  const int arl = lane >> 2;
  const int acl = (((lane & 3) ^ ((arl >> 1) & 3)) * 8);
  const int brl = lane >> 1;
  const int bcl = (((lane & 1) ^ ((brl >> 2) & 1)) * 16);
  const int cbx = (wave < 4) ? (4 + wave) : (wave - 4);

#define K5_STAGE(s_) {                                                                     \
    const int ss_ = (s_); const int kb_ = ss_ * 32; const int bf_ = ss_ & 3;               \
    gload16(Sp + (size_t)a0p * 262144 + (size_t)(mloc + a0q * 16 + arl) * 512 + kb_ + acl, \
            &As[bf_][a0p][a0q * 16][0]);                                                   \
    if (wave < 4)                                                                          \
      gload16(Sp + 2 * 262144 + (size_t)(mloc + wave * 16 + arl) * 512 + kb_ + acl,        \
              &As[bf_][2][wave * 16][0]);                                                  \
    gload16(Bb + (size_t)(cbx * 32 + brl) * 512 + kb_ + bcl, &Bs8[bf_][cbx * 32][0]);      \
  }

  f32x4 acc[8];
#pragma unroll
  for (int j = 0; j < 8; j++) acc[j] = (f32x4){0.f, 0.f, 0.f, 0.f};

  K5_STAGE(0);
  K5_STAGE(1);

  for (int s = 0; s < 16; s++) {
    const int cur = s & 3;
    if (s < 14) K5_STAGE(s + 2);

    if (s < 14) {
      if (wave < 4) asm volatile("s_waitcnt vmcnt(6)" ::: "memory");
      else          asm volatile("s_waitcnt vmcnt(4)" ::: "memory");
    } else if (s == 14) {
      if (wave < 4) asm volatile("s_waitcnt vmcnt(3)" ::: "memory");
      else          asm volatile("s_waitcnt vmcnt(2)" ::: "memory");
    } else {
      asm volatile("s_waitcnt vmcnt(0)" ::: "memory");
    }
    __builtin_amdgcn_s_barrier();
    __builtin_amdgcn_sched_barrier(0);

    bf16x8 af[3];
    const int ar = wrow + frow;
    const int asw = (fsl ^ ((ar >> 1) & 3)) * 8;
#pragma unroll
    for (int p = 0; p < 3; p++) af[p] = *(const bf16x8*)&As[cur][p][ar][asw];

#pragma unroll
    for (int j = 0; j < 8; j++) {
      const int row = wcol + j * 16 + frow;
      const int bsw = (fsl ^ (((row >> 2) & 1) << 1)) * 8;
      uint2 raw = *(const uint2*)&Bs8[cur][row][bsw];
      union { bf16x8 v; unsigned int u[4]; } bu;
      bu.u[0] = __builtin_amdgcn_perm(0u, raw.x, 0x05010400u) * 0x3F80u;
      bu.u[1] = __builtin_amdgcn_perm(0u, raw.x, 0x07030602u) * 0x3F80u;
      bu.u[2] = __builtin_amdgcn_perm(0u, raw.y, 0x05010400u) * 0x3F80u;
      bu.u[3] = __builtin_amdgcn_perm(0u, raw.y, 0x07030602u) * 0x3F80u;
#pragma unroll
      for (int p = 0; p < 3; p++)
        acc[j] = __builtin_amdgcn_mfma_f32_16x16x32_bf16(af[p], bu.v, acc[j], 0, 0, 0);
    }
  }

  const int crow0 = (lane >> 4) * 4;
  const int cn    = lane & 15;
#pragma unroll
  for (int r = 0; r < 4; r++) {
    const int c = mloc + wrow + crow0 + r;
    const float scf = psc[c];
    const float bif = pbi[c];
    const float bpf = bp[c];
#pragma unroll
    for (int j = 0; j < 8; j++) {
      const int n = wcol + j * 16 + cn;
      const size_t idx = ((size_t)tb * C_DIM + c) * N_DIM + n;
      out0[idx] = (acc[j][r] + bpf) * scf + bif + x[idx];
    }
  }
#undef K5_STAGE
}

// ---------------------------------------------------------------------------
// fp32 problem. d_out = 33,554,432 floats: out0 [0,16.7M), out1 [16.7M,33.5M).
// Scratch in out0 byte region (dead until K5 overwrites it):
//   o0+0    xsT8 16MB [K1->K2]  (aliased by attn 8MB [K3->K4])
//   o0+16M  qs8 16MB [K2->K4] ; o0+32M ks8 16MB [K2->K3]
//   o0+48M  Sqkv split 4.5MB [K0->K2]
// d_ws: x2sT8 16MB [K4->K5]; +16M Sp split 1.5MB [K0->K5].
// ---------------------------------------------------------------------------
extern "C" void kernel_launch(void* const* d_in, const int* in_sizes, int n_in,
                              void* d_out, int out_size, void* d_ws, size_t ws_size,
                              hipStream_t stream) {
  const float* x   = (const float*)d_in[0];
  const float* Wq  = (const float*)d_in[1];
  const float* qsc = (const float*)d_in[2];
  const float* qbi = (const float*)d_in[3];
  const float* Wk  = (const float*)d_in[4];
  const float* ksc = (const float*)d_in[5];
  const float* kbi = (const float*)d_in[6];
  const float* Wv  = (const float*)d_in[7];
  const float* vsc = (const float*)d_in[8];
  const float* vbi = (const float*)d_in[9];
  const float* Wp  = (const float*)d_in[10];
  const float* bp  = (const float*)d_in[11];
  const float* psc = (const float*)d_in[12];
  const float* pbi = (const float*)d_in[13];

  float* out0 = (float*)d_out;
  float* out1 = out0 + 16777216;

  const size_t M16 = 16u * 1024u * 1024u;
  char* o0 = (char*)d_out;
  char* ws = (char*)d_ws;

  u8*       xsT8  = (u8*)(o0);
  u8*       qs8   = (u8*)(o0 + M16);
  u8*       ks8   = (u8*)(o0 + 2 * M16);
  ushort_t* Sqkv  = (ushort_t*)(o0 + 3 * M16);
  float*    attn  = (float*)(o0);
  u8*       x2sT8 = (u8*)(ws);
  ushort_t* Sp    = (ushort_t*)(ws + M16);

  hipLaunchKernelGGL(k0_split,        dim3(512),        dim3(256), 0, stream,
                     Wq, Wk, Wv, Wp, Sqkv, Sp);
  hipLaunchKernelGGL(k1_shortcut_lif, dim3(4, 8, 32),   dim3(256), 0, stream, x, xsT8);
  hipLaunchKernelGGL(k2_qkv,          dim3(24, 32),     dim3(512), 0, stream,
                     xsT8, Sqkv, qsc, qbi, ksc, kbi, vsc, vbi, qs8, ks8, out1);
  hipLaunchKernelGGL(k3_attn,         dim3(8, 32, 2),   dim3(256), 0, stream, ks8, out1, attn);
  hipLaunchKernelGGL(k4_out_lif,      dim3(8, 32, 4),   dim3(256), 0, stream, qs8, attn, x2sT8);
  hipLaunchKernelGGL(k5_proj,         dim3(128, 8),     dim3(512), 0, stream,
                     x2sT8, Sp, bp, psc, pbi, x, out0);
}